// Round 1
// baseline (1438.970 us; speedup 1.0000x reference)
//
#include <hip/hip_runtime.h>

// Problem constants (B,C,H,W = 32,512,32,32)
#define B_N   32
#define C_N   512
#define HW_N  1024
#define C8_N  64
#define MQKV  640   // 64 (q) + 64 (k) + 512 (v) rows

// ---------------------------------------------------------------------------
// Kernel 1: fused QKV projection.
// qkv[b, m, p] = sum_c W[m,c] * x[b,c,p] + bias[m]
//   m in [0,64)    -> wq/bq
//   m in [64,128)  -> wk/bk
//   m in [128,640) -> wv/bv
// Batched GEMM M=640, K=512, N=1024.  64x64 tile, 4x4 microtile, K-chunk 16.
// ---------------------------------------------------------------------------
__global__ __launch_bounds__(256) void qkv_proj_kernel(
    const float* __restrict__ x,
    const float* __restrict__ wq, const float* __restrict__ bq,
    const float* __restrict__ wk, const float* __restrict__ bk,
    const float* __restrict__ wv, const float* __restrict__ bv,
    float* __restrict__ qkv)
{
    const int b   = blockIdx.z;
    const int m0  = blockIdx.y * 64;    // output row tile (0..639)
    const int p0  = blockIdx.x * 64;    // pixel tile
    const int tid = threadIdx.x;
    const int tx  = tid & 15;           // micro col group
    const int ty  = tid >> 4;           // micro row group

    // 64-row tiles never straddle the q/k/v boundaries (64,64,512 all 64-aligned)
    const float* wmat; const float* bvec; int mb;
    if (m0 < 64)       { wmat = wq; bvec = bq; mb = m0;       }
    else if (m0 < 128) { wmat = wk; bvec = bk; mb = m0 - 64;  }
    else               { wmat = wv; bvec = bv; mb = m0 - 128; }

    __shared__ float Ws[16][65];   // [c][m]  (+1 pad)
    __shared__ float Xs[16][65];   // [c][p]

    float acc[4][4] = {};
    const float* xb = x + (size_t)b * C_N * HW_N;

    for (int c0 = 0; c0 < C_N; c0 += 16) {
        {   // X tile: 16c x 64p, float4 along p
            const int c = tid >> 4;
            const int p = (tid & 15) * 4;
            const float4 t = *(const float4*)(xb + (size_t)(c0 + c) * HW_N + p0 + p);
            Xs[c][p + 0] = t.x; Xs[c][p + 1] = t.y;
            Xs[c][p + 2] = t.z; Xs[c][p + 3] = t.w;
        }
        {   // W tile: 64m x 16c, float4 along c, stored transposed [c][m]
            const int m = tid >> 2;
            const int c = (tid & 3) * 4;
            const float4 t = *(const float4*)(wmat + (size_t)(mb + m) * C_N + c0 + c);
            Ws[c + 0][m] = t.x; Ws[c + 1][m] = t.y;
            Ws[c + 2][m] = t.z; Ws[c + 3][m] = t.w;
        }
        __syncthreads();
        #pragma unroll
        for (int cc = 0; cc < 16; ++cc) {
            float am[4], bp[4];
            #pragma unroll
            for (int i = 0; i < 4; ++i) am[i] = Ws[cc][ty * 4 + i];
            #pragma unroll
            for (int j = 0; j < 4; ++j) bp[j] = Xs[cc][tx * 4 + j];
            #pragma unroll
            for (int i = 0; i < 4; ++i)
                #pragma unroll
                for (int j = 0; j < 4; ++j)
                    acc[i][j] = fmaf(am[i], bp[j], acc[i][j]);
        }
        __syncthreads();
    }

    #pragma unroll
    for (int i = 0; i < 4; ++i) {
        const int gm   = m0 + ty * 4 + i;
        const float bi = bvec[mb + ty * 4 + i];
        float4 r;
        r.x = acc[i][0] + bi; r.y = acc[i][1] + bi;
        r.z = acc[i][2] + bi; r.w = acc[i][3] + bi;
        *(float4*)(qkv + ((size_t)b * MQKV + gm) * HW_N + p0 + tx * 4) = r;
    }
}

// ---------------------------------------------------------------------------
// Kernel 2: energy[b,i,j] = sum_c q[b,c,i] * k[b,c,j]   (K = 64)
// Written straight into the attention region of d_out (softmaxed in place next).
// ---------------------------------------------------------------------------
__global__ __launch_bounds__(256) void energy_kernel(
    const float* __restrict__ qkv, float* __restrict__ att)
{
    const int b   = blockIdx.z;
    const int i0  = blockIdx.y * 64;
    const int j0  = blockIdx.x * 64;
    const int tid = threadIdx.x;
    const int tx  = tid & 15;
    const int ty  = tid >> 4;

    const float* q = qkv + (size_t)b * MQKV * HW_N;   // [64][1024]
    const float* k = q + (size_t)C8_N * HW_N;         // [64][1024]

    __shared__ float Qs[16][65];   // [c][i]
    __shared__ float Ks[16][65];   // [c][j]
    float acc[4][4] = {};

    for (int c0 = 0; c0 < C8_N; c0 += 16) {
        const int c = tid >> 4;
        const int u = (tid & 15) * 4;
        {
            const float4 t = *(const float4*)(q + (size_t)(c0 + c) * HW_N + i0 + u);
            Qs[c][u + 0] = t.x; Qs[c][u + 1] = t.y;
            Qs[c][u + 2] = t.z; Qs[c][u + 3] = t.w;
        }
        {
            const float4 t = *(const float4*)(k + (size_t)(c0 + c) * HW_N + j0 + u);
            Ks[c][u + 0] = t.x; Ks[c][u + 1] = t.y;
            Ks[c][u + 2] = t.z; Ks[c][u + 3] = t.w;
        }
        __syncthreads();
        #pragma unroll
        for (int cc = 0; cc < 16; ++cc) {
            float qi[4], kj[4];
            #pragma unroll
            for (int i = 0; i < 4; ++i) qi[i] = Qs[cc][ty * 4 + i];
            #pragma unroll
            for (int j = 0; j < 4; ++j) kj[j] = Ks[cc][tx * 4 + j];
            #pragma unroll
            for (int i = 0; i < 4; ++i)
                #pragma unroll
                for (int j = 0; j < 4; ++j)
                    acc[i][j] = fmaf(qi[i], kj[j], acc[i][j]);
        }
        __syncthreads();
    }

    #pragma unroll
    for (int i = 0; i < 4; ++i) {
        float4 r;
        r.x = acc[i][0]; r.y = acc[i][1]; r.z = acc[i][2]; r.w = acc[i][3];
        *(float4*)(att + ((size_t)b * HW_N + i0 + ty * 4 + i) * HW_N + j0 + tx * 4) = r;
    }
}

// ---------------------------------------------------------------------------
// Kernel 3: row softmax in place over the last axis (1024). One block per row.
// ---------------------------------------------------------------------------
__global__ __launch_bounds__(256) void softmax_kernel(float* __restrict__ att)
{
    const size_t row = blockIdx.x;                 // b*HW + i
    float* e = att + row * (size_t)HW_N;
    const int tid  = threadIdx.x;
    const int wv_  = tid >> 6;                     // wave id (wave64)
    const int lane = tid & 63;

    float4 v = ((const float4*)e)[tid];

    float m = fmaxf(fmaxf(v.x, v.y), fmaxf(v.z, v.w));
    #pragma unroll
    for (int off = 32; off > 0; off >>= 1)
        m = fmaxf(m, __shfl_down(m, off, 64));
    __shared__ float red[4];
    if (lane == 0) red[wv_] = m;
    __syncthreads();
    m = fmaxf(fmaxf(red[0], red[1]), fmaxf(red[2], red[3]));
    __syncthreads();   // red reused below

    float4 ex;
    ex.x = __expf(v.x - m); ex.y = __expf(v.y - m);
    ex.z = __expf(v.z - m); ex.w = __expf(v.w - m);
    float s = ex.x + ex.y + ex.z + ex.w;
    #pragma unroll
    for (int off = 32; off > 0; off >>= 1)
        s += __shfl_down(s, off, 64);
    if (lane == 0) red[wv_] = s;
    __syncthreads();
    s = red[0] + red[1] + red[2] + red[3];

    const float inv = 1.0f / s;
    ex.x *= inv; ex.y *= inv; ex.z *= inv; ex.w *= inv;
    ((float4*)e)[tid] = ex;
}

// ---------------------------------------------------------------------------
// Kernel 4: out[b,c,i] = sum_j v[b,c,j] * att[b,i,j]; fused epilogue
//   rgb = gamma*out + x ; hho = gamma*out + hha   (out never materialized)
// GEMM M=512 (c), N=1024 (i), K=1024 (j); both operands K-contiguous.
// ---------------------------------------------------------------------------
__global__ __launch_bounds__(256) void out_kernel(
    const float* __restrict__ qkv, const float* __restrict__ att,
    const float* __restrict__ x, const float* __restrict__ hha,
    const float* __restrict__ gamma,
    float* __restrict__ rgb, float* __restrict__ hho)
{
    const int b   = blockIdx.z;
    const int c0  = blockIdx.y * 64;
    const int i0  = blockIdx.x * 64;
    const int tid = threadIdx.x;
    const int tx  = tid & 15;    // i micro
    const int ty  = tid >> 4;    // c micro

    const float* v = qkv + ((size_t)b * MQKV + 128) * HW_N;  // [512][1024]
    const float* a = att + (size_t)b * HW_N * HW_N;          // [1024][1024]

    __shared__ float Vs[16][65];   // [j][c]
    __shared__ float As[16][65];   // [j][i]
    float acc[4][4] = {};

    for (int j0 = 0; j0 < HW_N; j0 += 16) {
        {   // V tile 64c x 16j, float4 along j, store transposed
            const int c = tid >> 2;
            const int j = (tid & 3) * 4;
            const float4 t = *(const float4*)(v + (size_t)(c0 + c) * HW_N + j0 + j);
            Vs[j + 0][c] = t.x; Vs[j + 1][c] = t.y;
            Vs[j + 2][c] = t.z; Vs[j + 3][c] = t.w;
        }
        {   // A tile 64i x 16j, float4 along j, store transposed
            const int i = tid >> 2;
            const int j = (tid & 3) * 4;
            const float4 t = *(const float4*)(a + (size_t)(i0 + i) * HW_N + j0 + j);
            As[j + 0][i] = t.x; As[j + 1][i] = t.y;
            As[j + 2][i] = t.z; As[j + 3][i] = t.w;
        }
        __syncthreads();
        #pragma unroll
        for (int jj = 0; jj < 16; ++jj) {
            float vc[4], ai[4];
            #pragma unroll
            for (int i = 0; i < 4; ++i) vc[i] = Vs[jj][ty * 4 + i];
            #pragma unroll
            for (int j = 0; j < 4; ++j) ai[j] = As[jj][tx * 4 + j];
            #pragma unroll
            for (int i = 0; i < 4; ++i)
                #pragma unroll
                for (int j = 0; j < 4; ++j)
                    acc[i][j] = fmaf(vc[i], ai[j], acc[i][j]);
        }
        __syncthreads();
    }

    const float g = gamma[0];
    #pragma unroll
    for (int i = 0; i < 4; ++i) {
        const int c = c0 + ty * 4 + i;
        const size_t base = ((size_t)b * C_N + c) * HW_N + i0 + tx * 4;
        const float4 xo = *(const float4*)(x + base);
        const float4 ho = *(const float4*)(hha + base);
        float4 r, h;
        r.x = fmaf(g, acc[i][0], xo.x); h.x = fmaf(g, acc[i][0], ho.x);
        r.y = fmaf(g, acc[i][1], xo.y); h.y = fmaf(g, acc[i][1], ho.y);
        r.z = fmaf(g, acc[i][2], xo.z); h.z = fmaf(g, acc[i][2], ho.z);
        r.w = fmaf(g, acc[i][3], xo.w); h.w = fmaf(g, acc[i][3], ho.w);
        *(float4*)(rgb + base) = r;
        *(float4*)(hho + base) = h;
    }
}

// ---------------------------------------------------------------------------
extern "C" void kernel_launch(void* const* d_in, const int* in_sizes, int n_in,
                              void* d_out, int out_size, void* d_ws, size_t ws_size,
                              hipStream_t stream)
{
    const float* x     = (const float*)d_in[0];
    const float* hha   = (const float*)d_in[1];
    const float* wq    = (const float*)d_in[2];
    const float* bq    = (const float*)d_in[3];
    const float* wk    = (const float*)d_in[4];
    const float* bk    = (const float*)d_in[5];
    const float* wv    = (const float*)d_in[6];
    const float* bv    = (const float*)d_in[7];
    const float* gamma = (const float*)d_in[8];

    float* out = (float*)d_out;
    float* att = out;                                        // [32,1024,1024]
    float* rgb = att + (size_t)B_N * HW_N * HW_N;            // [32,512,1024]
    float* hho = rgb + (size_t)B_N * C_N * HW_N;             // [32,512,1024]

    float* qkv = (float*)d_ws;   // [32,640,1024] floats = 80 MiB scratch

    qkv_proj_kernel<<<dim3(HW_N / 64, MQKV / 64, B_N), 256, 0, stream>>>(
        x, wq, bq, wk, bk, wv, bv, qkv);
    energy_kernel<<<dim3(HW_N / 64, HW_N / 64, B_N), 256, 0, stream>>>(qkv, att);
    softmax_kernel<<<dim3(B_N * HW_N), 256, 0, stream>>>(att);
    out_kernel<<<dim3(HW_N / 64, C_N / 64, B_N), 256, 0, stream>>>(
        qkv, att, x, hha, gamma, rgb, hho);
}